// Round 9
// baseline (70.025 us; speedup 1.0000x reference)
//
#include <hip/hip_runtime.h>

typedef float f32x4 __attribute__((ext_vector_type(4)));

// B=4096 rows, NPTS=4097 points, M=4096 outputs per row.
constexpr int NPTS = 4097;
constexpr int M    = 4096;
constexpr int TPB  = 256;   // 4 INDEPENDENT waves per block, one row per wave
constexpr int WPB  = 4;
constexpr int NG   = 16;    // groups of 4 elems per thread; 64 lanes*4*16 = 4096
// element e(j,lane) = j*256 + lane*4  (lane-contiguous 16B, coalesced)

// Per-group increments + intra-group inclusive prefix from two aligned quads.
// S = row misalignment (compile-time -> register selects, no scratch).
// NOTE: called identically in all 3 passes -> identical rounding.
template<int S>
__device__ __forceinline__ void group_u(const f32x4 a, const f32x4 c,
                                        const f32x4 tq, float tn,
                                        float (&u)[4], float (&xsj)[4])
{
    const float m[8] = {a.x, a.y, a.z, a.w, c.x, c.y, c.z, c.w};
    const float x0 = m[S+0], x1 = m[S+1], x2 = m[S+2], x3 = m[S+3], x4 = m[S+4];
    const float d0 = 0.5f * (tq.y - tq.x);
    const float d1 = 0.5f * (tq.z - tq.y);
    const float d2 = 0.5f * (tq.w - tq.z);
    const float d3 = 0.5f * (tn   - tq.w);
    const float i0 = d0 * (x0 + x1);
    const float i1 = d1 * (x1 + x2);
    const float i2 = d2 * (x2 + x3);
    const float i3 = d3 * (x3 + x4);
    u[0] = i0;
    u[1] = i0 + i1;
    u[2] = u[1] + i2;
    u[3] = u[2] + i3;
    xsj[0] = x1; xsj[1] = x2; xsj[2] = x3; xsj[3] = x4;
}

template<int S, bool RHALF>
__device__ __forceinline__ void wave_body(
    const float* __restrict__ x, const float* __restrict__ t,
    float r, float ny, float* __restrict__ out, int b, int B)
{
    const int lane = threadIdx.x & 63;
    // x row base = b*4097 floats; 4097 ≡ 1 (mod 4) -> (xrow - S), S=b&3, is
    // 16B-aligned. Last row (b=4095, S=3) reads end exactly at x's last
    // element; other rows over-read <=3 floats into the next row (in bounds).
    const float* __restrict__ xal = x + (size_t)b * NPTS - S;

    // ---- pass 1: scan. Persist only zbb[j] = ny + global prefix before
    //      element e(j,lane) (group base); everything else is recomputed. ----
    float zbb[NG];
    {
        float jacc = 0.f;   // total of all group-rows j' < j (wave-wide)
#pragma unroll 4
        for (int j = 0; j < NG; ++j) {
            const int e = j * 256 + lane * 4;
            const f32x4 a  = *(const f32x4*)(xal + e);
            const f32x4 c  = *(const f32x4*)(xal + e + 4);
            const f32x4 tq = *(const f32x4*)(t + e);
            float tn = __shfl_down(tq.x, 1, 64);
            if (lane == 63) tn = t[e + 4];
            float u[4], xsj[4];
            group_u<S>(a, c, tq, tn, u, xsj);
            // wave inclusive scan of this group-row's totals
            float inc = u[3];
#pragma unroll
            for (int d = 1; d < 64; d <<= 1) {
                float v = __shfl_up(inc, d, 64);
                if (lane >= d) inc += v;
            }
            zbb[j] = ny + jacc + (inc - u[3]);   // exclusive within row j
            jacc += __shfl(inc, 63, 64);         // row-j wave total
        }
    }

    // ---- pass 2: Gram/projection sums (f32, group-pairwise) ----
    float s0 = 0, s1 = 0, s2 = 0, s3 = 0, s4 = 0;
#pragma unroll 4
    for (int j = 0; j < NG; ++j) {
        const int e = j * 256 + lane * 4;
        const f32x4 a  = *(const f32x4*)(xal + e);
        const f32x4 c  = *(const f32x4*)(xal + e + 4);
        const f32x4 tq = *(const f32x4*)(t + e);
        float tn = __shfl_down(tq.x, 1, 64);
        if (lane == 63) tn = t[e + 4];
        float u[4], xsj[4];
        group_u<S>(a, c, tq, tn, u, xsj);
        float pzz = 0, pzw = 0, pww = 0, pxz = 0, pxw = 0;
#pragma unroll
        for (int i = 0; i < 4; ++i) {
            const float z  = zbb[j] + u[i];
            const float w  = RHALF ? sqrtf(z) : powf(z, r);
            const float xv = xsj[i];
            pzz = fmaf(z,  z, pzz);
            pzw = fmaf(z,  w, pzw);
            pww = fmaf(w,  w, pww);
            pxz = fmaf(xv, z, pxz);
            pxw = fmaf(xv, w, pxw);
        }
        s0 += pzz; s1 += pzw; s2 += pww; s3 += pxz; s4 += pxw;
    }
    // butterfly all-reduce: every lane gets the full row sums
#pragma unroll
    for (int mq = 1; mq < 64; mq <<= 1) {
        s0 += __shfl_xor(s0, mq, 64);
        s1 += __shfl_xor(s1, mq, 64);
        s2 += __shfl_xor(s2, mq, 64);
        s3 += __shfl_xor(s3, mq, 64);
        s4 += __shfl_xor(s4, mq, 64);
    }

    // ---- 2x2 normal-equations solve (f64, redundant per lane, no LDS) ----
    const double a0 = s0, a1 = s1, a2 = s2, a3 = s3, a4 = s4;
    const double det = a0 * a2 - a1 * a1;
    const double inv = 1.0 / det;
    const float c0 = (float)((a3 * a2 - a4 * a1) * inv);
    const float c1 = (float)((a4 * a0 - a3 * a1) * inv);
    if (lane == 0) {
        out[(size_t)b * 2 + 0] = c0;
        out[(size_t)b * 2 + 1] = c1;
    }

    // ---- pass 3: x_hat, res (coalesced f32x4 stores), r2 ----
    float* __restrict__ xhat = out + (size_t)B * 2 + (size_t)b * M;
    float* __restrict__ res  = xhat + (size_t)B * M;

    float r2 = 0.f;
#pragma unroll 4
    for (int j = 0; j < NG; ++j) {
        const int e = j * 256 + lane * 4;
        const f32x4 a  = *(const f32x4*)(xal + e);
        const f32x4 c  = *(const f32x4*)(xal + e + 4);
        const f32x4 tq = *(const f32x4*)(t + e);
        float tn = __shfl_down(tq.x, 1, 64);
        if (lane == 63) tn = t[e + 4];
        float u[4], xsj[4];
        group_u<S>(a, c, tq, tn, u, xsj);
        f32x4 hv, rv;
        float p = 0.f;
#pragma unroll
        for (int i = 0; i < 4; ++i) {
            const float z  = zbb[j] + u[i];
            const float w  = RHALF ? sqrtf(z) : powf(z, r);
            const float h  = c0 * z + c1 * w;
            const float ev = xsj[i] - h;
            hv[i] = h; rv[i] = ev;
            p = fmaf(ev, ev, p);
        }
        *(f32x4*)(xhat + e) = hv;
        *(f32x4*)(res  + e) = rv;
        r2 += p;
    }
#pragma unroll
    for (int mq = 1; mq < 64; mq <<= 1) r2 += __shfl_xor(r2, mq, 64);
    if (lane == 0)
        out[(size_t)B * 2 + 2 * (size_t)B * M + b] = r2;
}

__global__ __launch_bounds__(TPB, 8)
void vp_kernel(const float* __restrict__ x, const float* __restrict__ t,
               const float* __restrict__ params, float* __restrict__ out, int B)
{
    const float r   = params[0];
    const float ny  = params[1];
    const int   wid = threadIdx.x >> 6;
    const int   b   = blockIdx.x * WPB + wid;   // row per wave
    // b & 3 == wid (blockIdx*4 ≡ 0 mod 4) -> S is wave-uniform & compile-time

    if (r == 0.5f) {
        switch (wid) {
        case 0:  wave_body<0, true>(x, t, r, ny, out, b, B); break;
        case 1:  wave_body<1, true>(x, t, r, ny, out, b, B); break;
        case 2:  wave_body<2, true>(x, t, r, ny, out, b, B); break;
        default: wave_body<3, true>(x, t, r, ny, out, b, B); break;
        }
    } else {
        switch (wid) {
        case 0:  wave_body<0, false>(x, t, r, ny, out, b, B); break;
        case 1:  wave_body<1, false>(x, t, r, ny, out, b, B); break;
        case 2:  wave_body<2, false>(x, t, r, ny, out, b, B); break;
        default: wave_body<3, false>(x, t, r, ny, out, b, B); break;
        }
    }
}

extern "C" void kernel_launch(void* const* d_in, const int* in_sizes, int n_in,
                              void* d_out, int out_size, void* d_ws, size_t ws_size,
                              hipStream_t stream) {
    const float* x = (const float*)d_in[0];
    const float* t = (const float*)d_in[1];
    const float* p = (const float*)d_in[2];
    float* out     = (float*)d_out;
    const int B    = in_sizes[0] / NPTS;   // 4096

    vp_kernel<<<dim3(B / WPB), dim3(TPB), 0, stream>>>(x, t, p, out, B);
}

// Round 10
// 41.691 us; speedup vs baseline: 1.6796x; 1.6796x over previous
//
#include <hip/hip_runtime.h>

typedef float f32x4 __attribute__((ext_vector_type(4)));

// B=4096 rows, NPTS=4097 points, M=4096 outputs per row.
constexpr int NPTS = 4097;
constexpr int M    = 4096;
constexpr int TPB  = 256;   // 4 waves
constexpr int NW   = TPB / 64;
constexpr int NJ   = 4;     // 4 groups of 4 elements per thread; NJ*TPB*4 == M
// thread owns elements e(j) = j*1024 + tid*4 .. +3 (lane-contiguous)

struct Lds {
    float wt[NW][NJ];     // per-wave scanned group totals
    float gram[NW][6];    // per-wave Gram/projection partials (+Sxx)
};

// 4-element trapezoid scan from two aligned f32x4 loads; S = row misalignment
// (compile-time -> pure register selects, no scratch).
template<int S>
__device__ __forceinline__ void scan4(const f32x4 a, const f32x4 c,
                                      float d0, float d1, float d2, float d3,
                                      float (&xsj)[4], float (&zlj)[4], float& gsj)
{
    const float m[8] = {a.x, a.y, a.z, a.w, c.x, c.y, c.z, c.w};
    const float x0 = m[S+0], x1 = m[S+1], x2 = m[S+2], x3 = m[S+3], x4 = m[S+4];
    const float i0 = d0 * (x0 + x1);
    const float i1 = d1 * (x1 + x2);
    const float i2 = d2 * (x2 + x3);
    const float i3 = d3 * (x3 + x4);
    zlj[0] = i0;
    zlj[1] = i0 + i1;
    zlj[2] = zlj[1] + i2;
    zlj[3] = zlj[2] + i3;
    gsj = zlj[3];
    xsj[0] = x1; xsj[1] = x2; xsj[2] = x3; xsj[3] = x4;
}

template<int S, bool RHALF>
__device__ __forceinline__ void body(const float* __restrict__ x,
                                     const float* __restrict__ t,
                                     float r, float ny,
                                     float* __restrict__ out,
                                     int b, int B, Lds& L)
{
    const int tid  = threadIdx.x;
    const int lane = tid & 63;
    const int wid  = tid >> 6;

    // x row base = b*4097 floats; b*4097 ≡ b (mod 4) -> (xrow - S), S=b&3, is
    // 16B-aligned. Row b=4095 (S=3) reads end exactly at x's last element;
    // S<3 rows over-read <=3 floats into the next row (in bounds).
    const float* __restrict__ xal = x + (size_t)b * NPTS - S;

    float xs[NJ][4];   // x_sl = x[m+1]
    float zl[NJ][4];   // local scan, later z
    float gs[NJ];      // group sums

#pragma unroll
    for (int j = 0; j < NJ; ++j) {
        const int e = j * 1024 + tid * 4;
        const f32x4 a4 = *(const f32x4*)(xal + e);
        const f32x4 c4 = *(const f32x4*)(xal + e + 4);
        const f32x4 tq = *(const f32x4*)(t + e);       // aligned, L2-hot
        float tn = __shfl_down(tq.x, 1, 64);           // t[e+4] from lane+1
        if (lane == 63) tn = t[e + 4];
        const float d0 = 0.5f * (tq.y - tq.x);
        const float d1 = 0.5f * (tq.z - tq.y);
        const float d2 = 0.5f * (tq.w - tq.z);
        const float d3 = 0.5f * (tn   - tq.w);
        scan4<S>(a4, c4, d0, d1, d2, d3, xs[j], zl[j], gs[j]);
    }

    // ---- 4 simultaneous wave inclusive scans of group sums ----
    float sc[NJ];
#pragma unroll
    for (int c = 0; c < NJ; ++c) sc[c] = gs[c];
#pragma unroll
    for (int d = 1; d < 64; d <<= 1) {
#pragma unroll
        for (int c = 0; c < NJ; ++c) {
            float u = __shfl_up(sc[c], d, 64);
            if (lane >= d) sc[c] += u;
        }
    }
    if (lane == 63) {
#pragma unroll
        for (int c = 0; c < NJ; ++c) L.wt[wid][c] = sc[c];
    }
    __syncthreads();

    float woff[NJ] = {}, Tt[NJ] = {};
#pragma unroll
    for (int w = 0; w < NW; ++w) {
#pragma unroll
        for (int c = 0; c < NJ; ++c) {
            const float v = L.wt[w][c];
            Tt[c] += v;
            if (w < wid) woff[c] += v;
        }
    }
    // exclusive prefix per group; memory order = j-major, tid-minor
    float zb[NJ];
    {
        float jacc = 0.f;
#pragma unroll
        for (int j = 0; j < NJ; ++j) {
            zb[j] = ny + jacc + woff[j] + (sc[j] - gs[j]);
            jacc += Tt[j];
        }
    }

    // ---- z, w=z^r, Gram/projection sums in f32 (group-pairwise), + Sxx ----
    float s0 = 0, s1 = 0, s2 = 0, s3 = 0, s4 = 0, s5 = 0;
#pragma unroll
    for (int j = 0; j < NJ; ++j) {
        float pzz = 0, pzw = 0, pww = 0, pxz = 0, pxw = 0, pxx = 0;
#pragma unroll
        for (int i = 0; i < 4; ++i) {
            const float z = zb[j] + zl[j][i];
            zl[j][i] = z;
            const float w = RHALF ? sqrtf(z) : powf(z, r);
            const float xv = xs[j][i];
            pzz = fmaf(z,  z,  pzz);
            pzw = fmaf(z,  w,  pzw);
            pww = fmaf(w,  w,  pww);
            pxz = fmaf(xv, z,  pxz);
            pxw = fmaf(xv, w,  pxw);
            pxx = fmaf(xv, xv, pxx);
        }
        s0 += pzz; s1 += pzw; s2 += pww; s3 += pxz; s4 += pxw; s5 += pxx;
    }
#pragma unroll
    for (int d = 32; d > 0; d >>= 1) {
        s0 += __shfl_down(s0, d, 64);
        s1 += __shfl_down(s1, d, 64);
        s2 += __shfl_down(s2, d, 64);
        s3 += __shfl_down(s3, d, 64);
        s4 += __shfl_down(s4, d, 64);
        s5 += __shfl_down(s5, d, 64);
    }
    if (lane == 0) {
        L.gram[wid][0] = s0; L.gram[wid][1] = s1; L.gram[wid][2] = s2;
        L.gram[wid][3] = s3; L.gram[wid][4] = s4; L.gram[wid][5] = s5;
    }
    __syncthreads();

    // ---- 2x2 normal-equations solve (f64, redundant per-thread; LDS
    //      broadcast reads). r2 via LS identity: Sxx - c0*Sxz - c1*Sxw
    //      (exact at the optimum; error ~1e-3 vs threshold 7.44) ----
    double a0 = 0, a1 = 0, a2 = 0, a3 = 0, a4 = 0, a5 = 0;
#pragma unroll
    for (int w = 0; w < NW; ++w) {
        a0 += L.gram[w][0]; a1 += L.gram[w][1]; a2 += L.gram[w][2];
        a3 += L.gram[w][3]; a4 += L.gram[w][4]; a5 += L.gram[w][5];
    }
    const double det = a0 * a2 - a1 * a1;
    const double inv = 1.0 / det;
    const double c0d = (a3 * a2 - a4 * a1) * inv;
    const double c1d = (a4 * a0 - a3 * a1) * inv;
    const float c0 = (float)c0d;
    const float c1 = (float)c1d;
    if (tid == 0) {
        out[(size_t)b * 2 + 0] = c0;
        out[(size_t)b * 2 + 1] = c1;
        out[(size_t)B * 2 + 2 * (size_t)B * M + b] =
            (float)(a5 - c0d * a3 - c1d * a4);
    }

    // ---- x_hat, res (regular coalesced f32x4 stores); no trailing sync ----
    float* __restrict__ xhat = out + (size_t)B * 2 + (size_t)b * M;
    float* __restrict__ res  = xhat + (size_t)B * M;

#pragma unroll
    for (int j = 0; j < NJ; ++j) {
        const int e = j * 1024 + tid * 4;
        f32x4 hv, rv;
#pragma unroll
        for (int i = 0; i < 4; ++i) {
            const float z = zl[j][i];
            const float w = RHALF ? sqrtf(z) : powf(z, r);
            const float h  = c0 * z + c1 * w;
            hv[i] = h;
            rv[i] = xs[j][i] - h;
        }
        *(f32x4*)(xhat + e) = hv;
        *(f32x4*)(res  + e) = rv;
    }
}

__global__ __launch_bounds__(TPB)
void vp_kernel(const float* __restrict__ x, const float* __restrict__ t,
               const float* __restrict__ params, float* __restrict__ out, int B)
{
    __shared__ Lds L;
    const float r  = params[0];
    const float ny = params[1];
    const int  b   = blockIdx.x;

    if (r == 0.5f) {
        switch (b & 3) {
        case 0:  body<0, true>(x, t, r, ny, out, b, B, L); break;
        case 1:  body<1, true>(x, t, r, ny, out, b, B, L); break;
        case 2:  body<2, true>(x, t, r, ny, out, b, B, L); break;
        default: body<3, true>(x, t, r, ny, out, b, B, L); break;
        }
    } else {
        switch (b & 3) {
        case 0:  body<0, false>(x, t, r, ny, out, b, B, L); break;
        case 1:  body<1, false>(x, t, r, ny, out, b, B, L); break;
        case 2:  body<2, false>(x, t, r, ny, out, b, B, L); break;
        default: body<3, false>(x, t, r, ny, out, b, B, L); break;
        }
    }
}

extern "C" void kernel_launch(void* const* d_in, const int* in_sizes, int n_in,
                              void* d_out, int out_size, void* d_ws, size_t ws_size,
                              hipStream_t stream) {
    const float* x = (const float*)d_in[0];
    const float* t = (const float*)d_in[1];
    const float* p = (const float*)d_in[2];
    float* out     = (float*)d_out;
    const int B    = in_sizes[0] / NPTS;   // 4096

    vp_kernel<<<dim3(B), dim3(TPB), 0, stream>>>(x, t, p, out, B);
}